// Round 2
// baseline (291.198 us; speedup 1.0000x reference)
//
#include <hip/hip_runtime.h>
#include <cstdint>
#include <cstddef>

typedef __attribute__((ext_vector_type(8))) short short8;
typedef __attribute__((ext_vector_type(16))) float floatx16;

__device__ __forceinline__ unsigned short f2bf(float f) {
    union { float f; unsigned int u; } v; v.f = f;
    unsigned int r = v.u + 0x7fffu + ((v.u >> 16) & 1u);
    return (unsigned short)(r >> 16);
}

__device__ __forceinline__ void glds16(const void* g, void* l) {
    __builtin_amdgcn_global_load_lds(
        (const __attribute__((address_space(1))) void*)g,
        (__attribute__((address_space(3))) void*)l, 16, 0, 0);
}

// C/D layout (m74/m101, verified): col = lane&31, row = (r&3)+8*(r>>2)+4*kg
#define EPI_ROW(r, kg) (((r) & 3) + 8 * ((r) >> 2) + 4 * (kg))

// ============ OLD LDS core: 128x128 block, 2-barrier loop (kept for pv) ======
__device__ __forceinline__ void gemm_core(
    const unsigned short* __restrict__ Ab, int ldA,
    const unsigned short* __restrict__ Bb, int ldB,
    int K,
    unsigned short* __restrict__ As, unsigned short* __restrict__ Bs,
    floatx16 (&acc)[2][2])
{
    const int tid = threadIdx.x;
    const int wave = tid >> 6, lane = tid & 63;

    const unsigned short* gA[4];
    const unsigned short* gB[4];
#pragma unroll
    for (int i = 0; i < 4; ++i) {
        const int c = i * 256 + tid;
        const int row = c >> 3;
        const int l = (c & 7) ^ ((row ^ (row >> 3)) & 7);
        gA[i] = Ab + (size_t)row * ldA + l * 8;
        gB[i] = Bb + (size_t)row * ldB + l * 8;
    }
    const int arow = (wave >> 1) * 64 + (lane & 31);
    const int brow = (wave & 1) * 64 + (lane & 31);
    const int kg = lane >> 5;
    const int sw = (lane & 7) ^ ((lane >> 3) & 3);
    const unsigned short* pa = As + arow * 64;
    const unsigned short* pb = Bs + brow * 64;

    for (int k0 = 0; k0 < K; k0 += 64) {
#pragma unroll
        for (int i = 0; i < 4; ++i)
            glds16(gA[i] + k0, As + (size_t)(i * 256 + wave * 64) * 8);
#pragma unroll
        for (int i = 0; i < 4; ++i)
            glds16(gB[i] + k0, Bs + (size_t)(i * 256 + wave * 64) * 8);
        __syncthreads();
#pragma unroll
        for (int s = 0; s < 4; ++s) {
            const int o0 = ((2 * s + kg) ^ sw) * 8;
            const int o1 = o0 ^ 32;
            short8 a0 = *(const short8*)(pa + o0);
            short8 a1 = *(const short8*)(pa + 32 * 64 + o1);
            short8 b0 = *(const short8*)(pb + o0);
            short8 b1 = *(const short8*)(pb + 32 * 64 + o1);
            acc[0][0] = __builtin_amdgcn_mfma_f32_32x32x16_bf16(a0, b0, acc[0][0], 0, 0, 0);
            acc[0][1] = __builtin_amdgcn_mfma_f32_32x32x16_bf16(a0, b1, acc[0][1], 0, 0, 0);
            acc[1][0] = __builtin_amdgcn_mfma_f32_32x32x16_bf16(a1, b0, acc[1][0], 0, 0, 0);
            acc[1][1] = __builtin_amdgcn_mfma_f32_32x32x16_bf16(a1, b1, acc[1][1], 0, 0, 0);
        }
        __syncthreads();
    }
}

// ============ 256x256 8-phase core (T2+T3+T4+T5), BK=64, 512 thr ============
// 4 phases per K-tile; phase = one 128x128 C-quadrant. Quadrant order:
// (0,0),(0,1),(1,1),(1,0). Reg reuse: A ph1->ph2 / ph3->ph4; b0 ph1->ph4;
// b1 ph2->ph3.
// Stage schedule (all leads >= 4.5 phases; ledger-verified):
//   ph1: A(t+1,1)   [buf (t+1)&1; old data last read at t-1 ph3 -> safe]
//   ph2: A(t+2,0)   [buf t&1; A0 read finished at ph1 barrier]
//   ph3: B(t+2,0)   [buf t&1; B0 last LDS-read pre-ph1]
//   ph4: B(t+2,1)   [buf t&1; B1 last LDS-read pre-ph2]
// Waits (counted, never 0 in steady state):
//   W1 @ ph2-end: vmcnt(10) -> forces A(t,1) landed before ph3 reads it.
//   W2 @ ph4-end: vmcnt(8)  -> forces A(t+1,0),B(t+1,0),B(t+1,1) landed.
// Tail: t+2>=NT skips stages, so waits tighten to 8/2 then 0.
__device__ __forceinline__ void gemm256_core(
    const unsigned short* __restrict__ Ab, int ldA,
    const unsigned short* __restrict__ Bb, int ldB,
    int K,
    unsigned short* __restrict__ As, unsigned short* __restrict__ Bs,
    floatx16 (&acc)[4][2])
{
    const int tid = threadIdx.x;
    const int wave = tid >> 6, lane = tid & 63;
    const int wm = wave >> 2, wn = wave & 3;
    const int kg = lane >> 5;
    const int l31 = lane & 31;
    const int NT = K >> 6;

    const int grow = tid >> 3;
    const int gsl = (tid & 7) ^ ((grow ^ (grow >> 3)) & 7);   // key(grow)==key(grow+64)
    const unsigned short* gA = Ab + (size_t)grow * ldA + gsl * 8;
    const unsigned short* gB = Bb + (size_t)grow * ldB + gsl * 8;
    unsigned short* dA = As + wave * 512;
    unsigned short* dB = Bs + wave * 512;

#define STG_A(t, h) do { if ((t) < NT) { \
    const unsigned short* s_ = gA + (size_t)(h) * 128 * ldA + (t) * 64; \
    unsigned short* d_ = dA + ((((t) & 1) << 1) + (h)) * 8192; \
    glds16(s_, d_); glds16(s_ + (size_t)64 * ldA, d_ + 4096); } } while (0)
#define STG_B(t, h) do { if ((t) < NT) { \
    const unsigned short* s_ = gB + (size_t)(h) * 128 * ldB + (t) * 64; \
    unsigned short* d_ = dB + ((((t) & 1) << 1) + (h)) * 8192; \
    glds16(s_, d_); glds16(s_ + (size_t)64 * ldB, d_ + 4096); } } while (0)

    const int sw = (lane & 7) ^ ((lane >> 3) & 3);   // key(base + l31), 64-invariant
    const int swB = sw ^ ((wn & 1) << 2);            // B rows wn*32 + l31
    const int paoff = (wm * 64 + l31) * 64;
    const int pboff = (wn * 32 + l31) * 64;

    // prologue: tile0 all 4 halves + tile1 all 3 remaining-need halves;
    // wait retires tile0's ph1/ph2 needs (A0,B0,B1), leaves 4 stages in flight.
    STG_A(0, 0); STG_B(0, 0); STG_B(0, 1); STG_A(0, 1);
    STG_A(1, 0); STG_B(1, 0); STG_B(1, 1);
    asm volatile("s_waitcnt vmcnt(8)" ::: "memory");
    __builtin_amdgcn_s_barrier();

    short8 a0[4], a1[4], b0[4], b1[4];
    for (int t = 0; t < NT; ++t) {
        const unsigned short* pa = As + ((t & 1) << 1) * 8192 + paoff;
        const unsigned short* pb = Bs + ((t & 1) << 1) * 8192 + pboff;

        // ---- ph1: quadrant (0,0): read A-half0, read B-half0 ----
#pragma unroll
        for (int s = 0; s < 4; ++s) {
            const int oa = ((2 * s + kg) ^ sw) * 8;
            const int ob = ((2 * s + kg) ^ swB) * 8;
            a0[s] = *(const short8*)(pa + oa);
            a1[s] = *(const short8*)(pa + 2048 + (oa ^ 32));
            b0[s] = *(const short8*)(pb + ob);
        }
        STG_A(t + 1, 1);
        __builtin_amdgcn_s_barrier();
        __builtin_amdgcn_s_setprio(1);
#pragma unroll
        for (int s = 0; s < 4; ++s) {
            acc[0][0] = __builtin_amdgcn_mfma_f32_32x32x16_bf16(a0[s], b0[s], acc[0][0], 0, 0, 0);
            acc[0][1] = __builtin_amdgcn_mfma_f32_32x32x16_bf16(a1[s], b0[s], acc[0][1], 0, 0, 0);
        }
        __builtin_amdgcn_s_setprio(0);
        __builtin_amdgcn_s_barrier();

        // ---- ph2: quadrant (0,1): reuse A, read B-half1 ----
#pragma unroll
        for (int s = 0; s < 4; ++s) {
            const int ob = ((2 * s + kg) ^ swB) * 8;
            b1[s] = *(const short8*)(pb + 8192 + ob);
        }
        STG_A(t + 2, 0);
        __builtin_amdgcn_s_barrier();
        __builtin_amdgcn_s_setprio(1);
#pragma unroll
        for (int s = 0; s < 4; ++s) {
            acc[1][0] = __builtin_amdgcn_mfma_f32_32x32x16_bf16(a0[s], b1[s], acc[1][0], 0, 0, 0);
            acc[1][1] = __builtin_amdgcn_mfma_f32_32x32x16_bf16(a1[s], b1[s], acc[1][1], 0, 0, 0);
        }
        __builtin_amdgcn_s_setprio(0);
        if (t + 2 < NT)      { asm volatile("s_waitcnt vmcnt(10)" ::: "memory"); }
        else if (t + 1 < NT) { asm volatile("s_waitcnt vmcnt(8)"  ::: "memory"); }
        else                 { asm volatile("s_waitcnt vmcnt(0)"  ::: "memory"); }
        __builtin_amdgcn_s_barrier();

        // ---- ph3: quadrant (1,1): read A-half1, reuse b1 ----
#pragma unroll
        for (int s = 0; s < 4; ++s) {
            const int oa = ((2 * s + kg) ^ sw) * 8;
            a0[s] = *(const short8*)(pa + 8192 + oa);
            a1[s] = *(const short8*)(pa + 8192 + 2048 + (oa ^ 32));
        }
        STG_B(t + 2, 0);
        __builtin_amdgcn_s_barrier();
        __builtin_amdgcn_s_setprio(1);
#pragma unroll
        for (int s = 0; s < 4; ++s) {
            acc[2][0] = __builtin_amdgcn_mfma_f32_32x32x16_bf16(a0[s], b1[s], acc[2][0], 0, 0, 0);
            acc[2][1] = __builtin_amdgcn_mfma_f32_32x32x16_bf16(a1[s], b1[s], acc[2][1], 0, 0, 0);
        }
        __builtin_amdgcn_s_setprio(0);
        __builtin_amdgcn_s_barrier();

        // ---- ph4: quadrant (1,0): reuse A, reuse b0 ----
        STG_B(t + 2, 1);
        __builtin_amdgcn_s_barrier();
        __builtin_amdgcn_s_setprio(1);
#pragma unroll
        for (int s = 0; s < 4; ++s) {
            acc[3][0] = __builtin_amdgcn_mfma_f32_32x32x16_bf16(a0[s], b0[s], acc[3][0], 0, 0, 0);
            acc[3][1] = __builtin_amdgcn_mfma_f32_32x32x16_bf16(a1[s], b0[s], acc[3][1], 0, 0, 0);
        }
        __builtin_amdgcn_s_setprio(0);
        if (t + 2 < NT)      { asm volatile("s_waitcnt vmcnt(8)" ::: "memory"); }
        else if (t + 1 < NT) { asm volatile("s_waitcnt vmcnt(2)" ::: "memory"); }
        else                 { asm volatile("s_waitcnt vmcnt(0)" ::: "memory"); }
        __builtin_amdgcn_s_barrier();
    }
#undef STG_A
#undef STG_B
}

// ============ merged prep: fp32->bf16 converts + weight transpose-converts ====
__global__ __launch_bounds__(256) void prep_kernel(
    const float* __restrict__ x, const float* __restrict__ ctx,
    const float* __restrict__ Wq, const float* __restrict__ Wk, const float* __restrict__ Wv,
    unsigned short* __restrict__ xb, unsigned short* __restrict__ cb,
    unsigned short* __restrict__ Wt0, unsigned short* __restrict__ WtKV) {
    const int b = blockIdx.x;
    if (b < 16384) {
        int i = b * 256 + threadIdx.x;
        const float* in; unsigned short* out; int j;
        if (i < 2097152) { in = x; out = xb; j = i; }
        else { in = ctx; out = cb; j = i - 2097152; }
        float4 v = reinterpret_cast<const float4*>(in)[j];
        ushort4 o;
        o.x = f2bf(v.x); o.y = f2bf(v.y); o.z = f2bf(v.z); o.w = f2bf(v.w);
        reinterpret_cast<ushort4*>(out)[j] = o;
    } else {
        __shared__ float tile[32][33];
        const int z = b - 16384;
        const int w = z >> 10, t = z & 1023;
        const float* in = (w == 0) ? Wq : (w == 1) ? Wk : Wv;
        unsigned short* out = (w == 0) ? Wt0 : (w == 1) ? WtKV : (WtKV + 1024 * 1024);
        const int c0 = (t & 31) * 32, r0 = (t >> 5) * 32;
        const int tx = threadIdx.x & 31, ty = threadIdx.x >> 5;
#pragma unroll
        for (int j = 0; j < 4; ++j)
            tile[ty + j * 8][tx] = in[(size_t)(r0 + ty + j * 8) * 1024 + c0 + tx];
        __syncthreads();
#pragma unroll
        for (int j = 0; j < 4; ++j)
            out[(size_t)(c0 + ty + j * 8) * 1024 + r0 + tx] = f2bf(tile[tx][ty + j * 8]);
    }
}

// ============ mega QKV: 384 blocks of 256x256; Q (128) + KV (256) ============
// XCD swizzle (bijective, 384%8==0): XCD k gets work-ids [k*48, k*48+48) so
// the 4 (Q) / 8 (KV) blocks sharing an A-panel co-reside on one L2.
__global__ __launch_bounds__(512, 2) void qkv_kernel(
    const unsigned short* __restrict__ xb, const unsigned short* __restrict__ cb,
    const unsigned short* __restrict__ WtQ, const unsigned short* __restrict__ WtKV,
    const float* __restrict__ bq, const float* __restrict__ bk, const float* __restrict__ bv,
    unsigned short* __restrict__ Qb, unsigned short* __restrict__ Kb,
    unsigned short* __restrict__ Vt) {
    __shared__ unsigned short As[32768];
    __shared__ unsigned short Bs[32768];
    const int bi = blockIdx.x;
    const int i = (bi & 7) * 48 + (bi >> 3);
    const bool isQ = i < 128;
    int by, bx;
    const unsigned short *A, *B;
    if (isQ) {
        by = i >> 2; bx = i & 3;
        A = xb + (size_t)by * 256 * 1024;
        B = WtQ + (size_t)bx * 256 * 1024;
    } else {
        const int j = i - 128;
        by = j >> 3; bx = j & 7;
        A = cb + (size_t)by * 256 * 1024;
        B = WtKV + (size_t)bx * 256 * 1024;
    }
    floatx16 acc[4][2];
#pragma unroll
    for (int q = 0; q < 4; ++q)
#pragma unroll
        for (int h = 0; h < 2; ++h)
#pragma unroll
            for (int r = 0; r < 16; ++r) acc[q][h][r] = 0.f;

    gemm256_core(A, 1024, B, 1024, 1024, As, Bs, acc);

    const int tid = threadIdx.x;
    const int wave = tid >> 6, lane = tid & 63;
    const int wm = wave >> 2, wn = wave & 3;
    const int kg = lane >> 5, l31 = lane & 31;
    const int rowbase = by * 256 + wm * 64;
    const int colbase = bx * 256 + wn * 32 + l31;
#pragma unroll
    for (int q = 0; q < 4; ++q) {
        const int qm = q >> 1;
        const int qn = (q >> 1) ^ (q & 1);
        const int col = colbase + qn * 128;
        const bool isV = (!isQ) && (bx * 256 + qn * 128 >= 1024);
        if (!isV) {
            unsigned short* O = isQ ? Qb : Kb;
            const float bvv = isQ ? bq[col] : bk[col];
#pragma unroll
            for (int mt = 0; mt < 2; ++mt)
#pragma unroll
                for (int r = 0; r < 16; ++r) {
                    const int row = rowbase + qm * 128 + mt * 32 + EPI_ROW(r, kg);
                    O[(size_t)row * 1024 + col] = f2bf(acc[q][mt][r] + bvv);
                }
        } else {
            // V -> transposed write: Vt[b][colv][q]; 4 consecutive q per reg-quad
            const int colv = col - 1024;
            const float bvv = bv[colv];
#pragma unroll
            for (int mt = 0; mt < 2; ++mt) {
                const int rowg = rowbase + qm * 128 + mt * 32 + 4 * kg;
                const int bb = rowg >> 11, qb = rowg & 2047;
#pragma unroll
                for (int g = 0; g < 4; ++g) {
                    ushort4 u;
                    u.x = f2bf(acc[q][mt][g * 4 + 0] + bvv);
                    u.y = f2bf(acc[q][mt][g * 4 + 1] + bvv);
                    u.z = f2bf(acc[q][mt][g * 4 + 2] + bvv);
                    u.w = f2bf(acc[q][mt][g * 4 + 3] + bvv);
                    *reinterpret_cast<ushort4*>(Vt + (size_t)bb * 2097152 + (size_t)colv * 2048 + qb + 8 * g) = u;
                }
            }
        }
    }
}

// ============ P_unnorm = exp(Q K^T * scale); row sums -> l via atomics ========
__global__ __launch_bounds__(512, 2) void qkt_kernel(
    const unsigned short* __restrict__ Qb, const unsigned short* __restrict__ Kb,
    unsigned short* __restrict__ Sb, float* __restrict__ l) {
    __shared__ unsigned short As[32768];
    __shared__ unsigned short Bs[32768];
    const int bi = blockIdx.x;                   // 0..255
    const int i = (bi & 7) * 32 + (bi >> 3);     // XCD swizzle (256%8==0)
    const int z = i >> 6, j = i & 63;
    const int by = j >> 3, bx = j & 7;
    const unsigned short* A = Qb + (size_t)z * 2097152 + (size_t)by * 256 * 1024;
    const unsigned short* B = Kb + (size_t)z * 2097152 + (size_t)bx * 256 * 1024;
    floatx16 acc[4][2];
#pragma unroll
    for (int q = 0; q < 4; ++q)
#pragma unroll
        for (int h = 0; h < 2; ++h)
#pragma unroll
            for (int r = 0; r < 16; ++r) acc[q][h][r] = 0.f;

    gemm256_core(A, 1024, B, 1024, 1024, As, Bs, acc);

    const int tid = threadIdx.x;
    const int wave = tid >> 6, lane = tid & 63;
    const int wm = wave >> 2, wn = wave & 3;
    const int kg = lane >> 5, l31 = lane & 31;
    unsigned short* C = Sb + (size_t)z * 4194304;
    float* lz = l + z * 2048;
    const int rowbase = by * 256 + wm * 64;
    const int colbase = bx * 256 + wn * 32 + l31;
    // quadrant pairs sharing rows: qm=0 -> q0 (qn0) + q1 (qn1); qm=1 -> q3 + q2
#pragma unroll
    for (int h = 0; h < 2; ++h) {
        const int qA = h ? 3 : 0;   // qn = 0
        const int qB = h ? 2 : 1;   // qn = 1
#pragma unroll
        for (int mt = 0; mt < 2; ++mt)
#pragma unroll
            for (int r = 0; r < 16; ++r) {
                const int row = rowbase + h * 128 + mt * 32 + EPI_ROW(r, kg);
                const float e0 = __expf(acc[qA][mt][r] * 0.03125f);
                const float e1 = __expf(acc[qB][mt][r] * 0.03125f);
                C[(size_t)row * 2048 + colbase] = f2bf(e0);
                C[(size_t)row * 2048 + colbase + 128] = f2bf(e1);
                float s = e0 + e1;
                s += __shfl_xor(s, 1);  s += __shfl_xor(s, 2);
                s += __shfl_xor(s, 4);  s += __shfl_xor(s, 8);
                s += __shfl_xor(s, 16);
                if (l31 == mt * 16 + r) atomicAdd(&lz[row], s);
            }
    }
}

// ============ out = (P_unnorm @ Vt^T) / l[row] (fp32 out) ============
__global__ __launch_bounds__(256, 4) void pv_kernel(
    const unsigned short* __restrict__ Sb, const unsigned short* __restrict__ Vt,
    const float* __restrict__ l, float* __restrict__ out) {
    __shared__ unsigned short As[128 * 64];
    __shared__ unsigned short Bs[128 * 64];
    const int i = blockIdx.x;                    // 0..511
    const int z = (i >> 1) & 3;
    const int slot = i >> 3;
    const int by = (i & 1) + 2 * (slot & 7);
    const int bx = slot >> 3;
    const unsigned short* A = Sb + (size_t)z * 4194304 + (size_t)by * 128 * 2048;
    const unsigned short* B = Vt + (size_t)z * 2097152 + (size_t)bx * 128 * 2048;
    floatx16 acc[2][2];
#pragma unroll
    for (int a = 0; a < 2; ++a)
#pragma unroll
        for (int bj = 0; bj < 2; ++bj)
#pragma unroll
            for (int r = 0; r < 16; ++r) acc[a][bj][r] = 0.f;

    gemm_core(A, 2048, B, 2048, 2048, As, Bs, acc);

    const int wave = threadIdx.x >> 6, lane = threadIdx.x & 63;
    const int kg = lane >> 5;
    float* C = out + (size_t)z * 2097152;
    const float* lz = l + z * 2048;
    const int cm = by * 128 + (wave >> 1) * 64;
    const int cn = bx * 128 + (wave & 1) * 64 + (lane & 31);
#pragma unroll
    for (int mt = 0; mt < 2; ++mt)
#pragma unroll
        for (int r = 0; r < 16; ++r) {
            const int row = cm + mt * 32 + EPI_ROW(r, kg);
            const float inv = 1.0f / lz[row];
            C[(size_t)row * 1024 + cn] = acc[mt][0][r] * inv;
            C[(size_t)row * 1024 + cn + 32] = acc[mt][1][r] * inv;
        }
}

extern "C" void kernel_launch(void* const* d_in, const int* in_sizes, int n_in,
                              void* d_out, int out_size, void* d_ws, size_t ws_size,
                              hipStream_t stream) {
    const float* x   = (const float*)d_in[0];
    const float* ctx = (const float*)d_in[1];
    const float* Wq  = (const float*)d_in[2];
    const float* bq  = (const float*)d_in[3];
    const float* Wk  = (const float*)d_in[4];
    const float* bk  = (const float*)d_in[5];
    const float* Wv  = (const float*)d_in[6];
    const float* bv  = (const float*)d_in[7];
    float* out = (float*)d_out;

    const size_t MB = 1024 * 1024;
    char* ws = (char*)d_ws;
    unsigned short* xb   = (unsigned short*)(ws + 0 * MB);
    unsigned short* cb   = (unsigned short*)(ws + 16 * MB);
    unsigned short* Qb   = (unsigned short*)(ws + 32 * MB);
    unsigned short* Kb   = (unsigned short*)(ws + 48 * MB);
    unsigned short* Vt   = (unsigned short*)(ws + 64 * MB);
    unsigned short* Wt0  = (unsigned short*)(ws + 80 * MB);
    unsigned short* WtKV = (unsigned short*)(ws + 82 * MB);
    unsigned short* Sb   = (unsigned short*)(ws + 86 * MB);
    float*          lrow = (float*)(ws + 118 * MB);   // 8192 fp32 row sums

    hipMemsetAsync(lrow, 0, 8192 * sizeof(float), stream);
    prep_kernel<<<16384 + 3072, 256, 0, stream>>>(x, ctx, Wq, Wk, Wv, xb, cb, Wt0, WtKV);
    qkv_kernel<<<384, 512, 0, stream>>>(xb, cb, Wt0, WtKV, bq, bk, bv, Qb, Kb, Vt);
    qkt_kernel<<<256, 512, 0, stream>>>(Qb, Kb, Sb, lrow);
    pv_kernel<<<512, 256, 0, stream>>>(Sb, Vt, lrow, out);
}

// Round 3
// 285.932 us; speedup vs baseline: 1.0184x; 1.0184x over previous
//
#include <hip/hip_runtime.h>
#include <cstdint>
#include <cstddef>

typedef __attribute__((ext_vector_type(8))) short short8;
typedef __attribute__((ext_vector_type(16))) float floatx16;

__device__ __forceinline__ unsigned short f2bf(float f) {
    union { float f; unsigned int u; } v; v.f = f;
    unsigned int r = v.u + 0x7fffu + ((v.u >> 16) & 1u);
    return (unsigned short)(r >> 16);
}

__device__ __forceinline__ void glds16(const void* g, void* l) {
    __builtin_amdgcn_global_load_lds(
        (const __attribute__((address_space(1))) void*)g,
        (__attribute__((address_space(3))) void*)l, 16, 0, 0);
}

// C/D layout (m74/m101, verified): col = lane&31, row = (r&3)+8*(r>>2)+4*kg
#define EPI_ROW(r, kg) (((r) & 3) + 8 * ((r) >> 2) + 4 * (kg))

// ============ 128x128 core, 2-barrier loop (measured ~810 TF @ >=2 blk/CU) ===
__device__ __forceinline__ void gemm_core(
    const unsigned short* __restrict__ Ab, int ldA,
    const unsigned short* __restrict__ Bb, int ldB,
    int K,
    unsigned short* __restrict__ As, unsigned short* __restrict__ Bs,
    floatx16 (&acc)[2][2])
{
    const int tid = threadIdx.x;
    const int wave = tid >> 6, lane = tid & 63;

    const unsigned short* gA[4];
    const unsigned short* gB[4];
#pragma unroll
    for (int i = 0; i < 4; ++i) {
        const int c = i * 256 + tid;
        const int row = c >> 3;
        const int l = (c & 7) ^ ((row ^ (row >> 3)) & 7);
        gA[i] = Ab + (size_t)row * ldA + l * 8;
        gB[i] = Bb + (size_t)row * ldB + l * 8;
    }
    const int arow = (wave >> 1) * 64 + (lane & 31);
    const int brow = (wave & 1) * 64 + (lane & 31);
    const int kg = lane >> 5;
    const int sw = (lane & 7) ^ ((lane >> 3) & 3);
    const unsigned short* pa = As + arow * 64;
    const unsigned short* pb = Bs + brow * 64;

    for (int k0 = 0; k0 < K; k0 += 64) {
#pragma unroll
        for (int i = 0; i < 4; ++i)
            glds16(gA[i] + k0, As + (size_t)(i * 256 + wave * 64) * 8);
#pragma unroll
        for (int i = 0; i < 4; ++i)
            glds16(gB[i] + k0, Bs + (size_t)(i * 256 + wave * 64) * 8);
        __syncthreads();
#pragma unroll
        for (int s = 0; s < 4; ++s) {
            const int o0 = ((2 * s + kg) ^ sw) * 8;
            const int o1 = o0 ^ 32;
            short8 a0 = *(const short8*)(pa + o0);
            short8 a1 = *(const short8*)(pa + 32 * 64 + o1);
            short8 b0 = *(const short8*)(pb + o0);
            short8 b1 = *(const short8*)(pb + 32 * 64 + o1);
            acc[0][0] = __builtin_amdgcn_mfma_f32_32x32x16_bf16(a0, b0, acc[0][0], 0, 0, 0);
            acc[0][1] = __builtin_amdgcn_mfma_f32_32x32x16_bf16(a0, b1, acc[0][1], 0, 0, 0);
            acc[1][0] = __builtin_amdgcn_mfma_f32_32x32x16_bf16(a1, b0, acc[1][0], 0, 0, 0);
            acc[1][1] = __builtin_amdgcn_mfma_f32_32x32x16_bf16(a1, b1, acc[1][1], 0, 0, 0);
        }
        __syncthreads();
    }
}

// ============ 256x256 8-phase core (T2+T3+T4+T5), BK=64, 512 thr ============
// Intrinsic rate ~915 TF-equiv (r2: 384 blocks -> 2 rounds -> 75us => T=37.5us
// per 0.134 GF block). Must be launched with grid that packs 256 CUs evenly.
__device__ __forceinline__ void gemm256_core(
    const unsigned short* __restrict__ Ab, int ldA,
    const unsigned short* __restrict__ Bb, int ldB,
    int K,
    unsigned short* __restrict__ As, unsigned short* __restrict__ Bs,
    floatx16 (&acc)[4][2])
{
    const int tid = threadIdx.x;
    const int wave = tid >> 6, lane = tid & 63;
    const int wm = wave >> 2, wn = wave & 3;
    const int kg = lane >> 5;
    const int l31 = lane & 31;
    const int NT = K >> 6;

    const int grow = tid >> 3;
    const int gsl = (tid & 7) ^ ((grow ^ (grow >> 3)) & 7);   // key(grow)==key(grow+64)
    const unsigned short* gA = Ab + (size_t)grow * ldA + gsl * 8;
    const unsigned short* gB = Bb + (size_t)grow * ldB + gsl * 8;
    unsigned short* dA = As + wave * 512;
    unsigned short* dB = Bs + wave * 512;

#define STG_A(t, h) do { if ((t) < NT) { \
    const unsigned short* s_ = gA + (size_t)(h) * 128 * ldA + (t) * 64; \
    unsigned short* d_ = dA + ((((t) & 1) << 1) + (h)) * 8192; \
    glds16(s_, d_); glds16(s_ + (size_t)64 * ldA, d_ + 4096); } } while (0)
#define STG_B(t, h) do { if ((t) < NT) { \
    const unsigned short* s_ = gB + (size_t)(h) * 128 * ldB + (t) * 64; \
    unsigned short* d_ = dB + ((((t) & 1) << 1) + (h)) * 8192; \
    glds16(s_, d_); glds16(s_ + (size_t)64 * ldB, d_ + 4096); } } while (0)

    const int sw = (lane & 7) ^ ((lane >> 3) & 3);   // key(base + l31), 64-invariant
    const int swB = sw ^ ((wn & 1) << 2);            // B rows wn*32 + l31
    const int paoff = (wm * 64 + l31) * 64;
    const int pboff = (wn * 32 + l31) * 64;

    // prologue: tile0 all 4 halves + tile1's 3 early-need halves.
    STG_A(0, 0); STG_B(0, 0); STG_B(0, 1); STG_A(0, 1);
    STG_A(1, 0); STG_B(1, 0); STG_B(1, 1);
    asm volatile("s_waitcnt vmcnt(8)" ::: "memory");
    __builtin_amdgcn_s_barrier();

    short8 a0[4], a1[4], b0[4], b1[4];
    for (int t = 0; t < NT; ++t) {
        const unsigned short* pa = As + ((t & 1) << 1) * 8192 + paoff;
        const unsigned short* pb = Bs + ((t & 1) << 1) * 8192 + pboff;

        // ---- ph1: quadrant (0,0): read A-half0, read B-half0 ----
#pragma unroll
        for (int s = 0; s < 4; ++s) {
            const int oa = ((2 * s + kg) ^ sw) * 8;
            const int ob = ((2 * s + kg) ^ swB) * 8;
            a0[s] = *(const short8*)(pa + oa);
            a1[s] = *(const short8*)(pa + 2048 + (oa ^ 32));
            b0[s] = *(const short8*)(pb + ob);
        }
        STG_A(t + 1, 1);
        __builtin_amdgcn_s_barrier();
        __builtin_amdgcn_s_setprio(1);
#pragma unroll
        for (int s = 0; s < 4; ++s) {
            acc[0][0] = __builtin_amdgcn_mfma_f32_32x32x16_bf16(a0[s], b0[s], acc[0][0], 0, 0, 0);
            acc[0][1] = __builtin_amdgcn_mfma_f32_32x32x16_bf16(a1[s], b0[s], acc[0][1], 0, 0, 0);
        }
        __builtin_amdgcn_s_setprio(0);
        __builtin_amdgcn_s_barrier();

        // ---- ph2: quadrant (0,1): reuse A, read B-half1 ----
#pragma unroll
        for (int s = 0; s < 4; ++s) {
            const int ob = ((2 * s + kg) ^ swB) * 8;
            b1[s] = *(const short8*)(pb + 8192 + ob);
        }
        STG_A(t + 2, 0);
        __builtin_amdgcn_s_barrier();
        __builtin_amdgcn_s_setprio(1);
#pragma unroll
        for (int s = 0; s < 4; ++s) {
            acc[1][0] = __builtin_amdgcn_mfma_f32_32x32x16_bf16(a0[s], b1[s], acc[1][0], 0, 0, 0);
            acc[1][1] = __builtin_amdgcn_mfma_f32_32x32x16_bf16(a1[s], b1[s], acc[1][1], 0, 0, 0);
        }
        __builtin_amdgcn_s_setprio(0);
        if (t + 2 < NT)      { asm volatile("s_waitcnt vmcnt(10)" ::: "memory"); }
        else if (t + 1 < NT) { asm volatile("s_waitcnt vmcnt(8)"  ::: "memory"); }
        else                 { asm volatile("s_waitcnt vmcnt(0)"  ::: "memory"); }
        __builtin_amdgcn_s_barrier();

        // ---- ph3: quadrant (1,1): read A-half1, reuse b1 ----
#pragma unroll
        for (int s = 0; s < 4; ++s) {
            const int oa = ((2 * s + kg) ^ sw) * 8;
            a0[s] = *(const short8*)(pa + 8192 + oa);
            a1[s] = *(const short8*)(pa + 8192 + 2048 + (oa ^ 32));
        }
        STG_B(t + 2, 0);
        __builtin_amdgcn_s_barrier();
        __builtin_amdgcn_s_setprio(1);
#pragma unroll
        for (int s = 0; s < 4; ++s) {
            acc[2][0] = __builtin_amdgcn_mfma_f32_32x32x16_bf16(a0[s], b1[s], acc[2][0], 0, 0, 0);
            acc[2][1] = __builtin_amdgcn_mfma_f32_32x32x16_bf16(a1[s], b1[s], acc[2][1], 0, 0, 0);
        }
        __builtin_amdgcn_s_setprio(0);
        __builtin_amdgcn_s_barrier();

        // ---- ph4: quadrant (1,0): reuse A, reuse b0 ----
        STG_B(t + 2, 1);
        __builtin_amdgcn_s_barrier();
        __builtin_amdgcn_s_setprio(1);
#pragma unroll
        for (int s = 0; s < 4; ++s) {
            acc[3][0] = __builtin_amdgcn_mfma_f32_32x32x16_bf16(a0[s], b0[s], acc[3][0], 0, 0, 0);
            acc[3][1] = __builtin_amdgcn_mfma_f32_32x32x16_bf16(a1[s], b0[s], acc[3][1], 0, 0, 0);
        }
        __builtin_amdgcn_s_setprio(0);
        if (t + 2 < NT)      { asm volatile("s_waitcnt vmcnt(8)" ::: "memory"); }
        else if (t + 1 < NT) { asm volatile("s_waitcnt vmcnt(2)" ::: "memory"); }
        else                 { asm volatile("s_waitcnt vmcnt(0)" ::: "memory"); }
        __builtin_amdgcn_s_barrier();
    }
#undef STG_A
#undef STG_B
}

// ====== prep: fp32->bf16 converts + weight transpose-converts + lrow zero ====
__global__ __launch_bounds__(256) void prep_kernel(
    const float* __restrict__ x, const float* __restrict__ ctx,
    const float* __restrict__ Wq, const float* __restrict__ Wk, const float* __restrict__ Wv,
    unsigned short* __restrict__ xb, unsigned short* __restrict__ cb,
    unsigned short* __restrict__ Wt0, unsigned short* __restrict__ WtKV,
    float* __restrict__ lrow) {
    const int b = blockIdx.x;
    if (b < 16384) {
        int i = b * 256 + threadIdx.x;
        const float* in; unsigned short* out; int j;
        if (i < 2097152) { in = x; out = xb; j = i; }
        else { in = ctx; out = cb; j = i - 2097152; }
        float4 v = reinterpret_cast<const float4*>(in)[j];
        ushort4 o;
        o.x = f2bf(v.x); o.y = f2bf(v.y); o.z = f2bf(v.z); o.w = f2bf(v.w);
        reinterpret_cast<ushort4*>(out)[j] = o;
    } else if (b < 19456) {
        __shared__ float tile[32][33];
        const int z = b - 16384;
        const int w = z >> 10, t = z & 1023;
        const float* in = (w == 0) ? Wq : (w == 1) ? Wk : Wv;
        unsigned short* out = (w == 0) ? Wt0 : (w == 1) ? WtKV : (WtKV + 1024 * 1024);
        const int c0 = (t & 31) * 32, r0 = (t >> 5) * 32;
        const int tx = threadIdx.x & 31, ty = threadIdx.x >> 5;
#pragma unroll
        for (int j = 0; j < 4; ++j)
            tile[ty + j * 8][tx] = in[(size_t)(r0 + ty + j * 8) * 1024 + c0 + tx];
        __syncthreads();
#pragma unroll
        for (int j = 0; j < 4; ++j)
            out[(size_t)(c0 + ty + j * 8) * 1024 + r0 + tx] = f2bf(tile[tx][ty + j * 8]);
    } else {
        // zero lrow: 8192 floats = 2048 float4 over 8 blocks x 256 threads
        const int i = (b - 19456) * 256 + threadIdx.x;
        reinterpret_cast<float4*>(lrow)[i] = float4{0.f, 0.f, 0.f, 0.f};
    }
}

// ============ KV GEMM: exactly 256 blocks of 256x256 (8-phase core) ==========
// XCD swizzle: XCD k gets by in [4k,4k+4) x all bx -> A-panels shared in-L2.
__global__ __launch_bounds__(512, 2) void qkv_kv_kernel(
    const unsigned short* __restrict__ cb, const unsigned short* __restrict__ WtKV,
    const float* __restrict__ bk, const float* __restrict__ bv,
    unsigned short* __restrict__ Kb, unsigned short* __restrict__ Vt) {
    __shared__ unsigned short As[32768];
    __shared__ unsigned short Bs[32768];
    const int bi = blockIdx.x;                 // 0..255
    const int i = (bi & 7) * 32 + (bi >> 3);   // bijective (256%8==0)
    const int by = i >> 3, bx = i & 7;
    const unsigned short* A = cb + (size_t)by * 256 * 1024;
    const unsigned short* B = WtKV + (size_t)bx * 256 * 1024;
    floatx16 acc[4][2];
#pragma unroll
    for (int q = 0; q < 4; ++q)
#pragma unroll
        for (int h = 0; h < 2; ++h)
#pragma unroll
            for (int r = 0; r < 16; ++r) acc[q][h][r] = 0.f;

    gemm256_core(A, 1024, B, 1024, 1024, As, Bs, acc);

    const int tid = threadIdx.x;
    const int wave = tid >> 6, lane = tid & 63;
    const int wm = wave >> 2, wn = wave & 3;
    const int kg = lane >> 5, l31 = lane & 31;
    const int rowbase = by * 256 + wm * 64;
    const int colbase = bx * 256 + wn * 32 + l31;
#pragma unroll
    for (int q = 0; q < 4; ++q) {
        const int qm = q >> 1;
        const int qn = (q >> 1) ^ (q & 1);
        const int col = colbase + qn * 128;
        if (bx * 256 + qn * 128 < 1024) {
            const float bvv = bk[col];
#pragma unroll
            for (int mt = 0; mt < 2; ++mt)
#pragma unroll
                for (int r = 0; r < 16; ++r) {
                    const int row = rowbase + qm * 128 + mt * 32 + EPI_ROW(r, kg);
                    Kb[(size_t)row * 1024 + col] = f2bf(acc[q][mt][r] + bvv);
                }
        } else {
            // V -> transposed write: Vt[b][colv][q]; 4 consecutive q per reg-quad
            const int colv = col - 1024;
            const float bvv = bv[colv];
#pragma unroll
            for (int mt = 0; mt < 2; ++mt) {
                const int rowg = rowbase + qm * 128 + mt * 32 + 4 * kg;
                const int bb = rowg >> 11, qb = rowg & 2047;
#pragma unroll
                for (int g = 0; g < 4; ++g) {
                    ushort4 u;
                    u.x = f2bf(acc[q][mt][g * 4 + 0] + bvv);
                    u.y = f2bf(acc[q][mt][g * 4 + 1] + bvv);
                    u.z = f2bf(acc[q][mt][g * 4 + 2] + bvv);
                    u.w = f2bf(acc[q][mt][g * 4 + 3] + bvv);
                    *reinterpret_cast<ushort4*>(Vt + (size_t)bb * 2097152 + (size_t)colv * 2048 + qb + 8 * g) = u;
                }
            }
        }
    }
}

// ============ Q GEMM: 512 blocks of 128x128 (2-barrier core, 2 blk/CU) =======
__global__ __launch_bounds__(256, 4) void qkv_q_kernel(
    const unsigned short* __restrict__ xb, const unsigned short* __restrict__ WtQ,
    const float* __restrict__ bq, unsigned short* __restrict__ Qb) {
    __shared__ unsigned short As[128 * 64];
    __shared__ unsigned short Bs[128 * 64];
    const int i = blockIdx.x;                    // 0..511
    const int slot = i >> 3;
    const int by = (i & 7) + 8 * (slot & 7);     // i%8==by%8: XCD co-location
    const int bx = slot >> 3;
    const unsigned short* A = xb + (size_t)by * 128 * 1024;
    const unsigned short* B = WtQ + (size_t)bx * 128 * 1024;
    floatx16 acc[2][2];
#pragma unroll
    for (int a = 0; a < 2; ++a)
#pragma unroll
        for (int bj = 0; bj < 2; ++bj)
#pragma unroll
            for (int r = 0; r < 16; ++r) acc[a][bj][r] = 0.f;

    gemm_core(A, 1024, B, 1024, 1024, As, Bs, acc);

    const int wave = threadIdx.x >> 6, lane = threadIdx.x & 63;
    const int kg = lane >> 5;
    const int cm = by * 128 + (wave >> 1) * 64;
    const int cn = bx * 128 + (wave & 1) * 64 + (lane & 31);
#pragma unroll
    for (int nt = 0; nt < 2; ++nt) {
        const int col = cn + nt * 32;
        const float bvv = bq[col];
#pragma unroll
        for (int mt = 0; mt < 2; ++mt)
#pragma unroll
            for (int r = 0; r < 16; ++r) {
                const int row = cm + mt * 32 + EPI_ROW(r, kg);
                Qb[(size_t)row * 1024 + col] = f2bf(acc[mt][nt][r] + bvv);
            }
    }
}

// ============ P_unnorm = exp(Q K^T * scale); row sums -> l via atomics ========
// 256 blocks of 256x256 (8-phase core) -- exactly 1 block/CU round.
__global__ __launch_bounds__(512, 2) void qkt_kernel(
    const unsigned short* __restrict__ Qb, const unsigned short* __restrict__ Kb,
    unsigned short* __restrict__ Sb, float* __restrict__ l) {
    __shared__ unsigned short As[32768];
    __shared__ unsigned short Bs[32768];
    const int bi = blockIdx.x;                   // 0..255
    const int i = (bi & 7) * 32 + (bi >> 3);     // XCD swizzle (256%8==0)
    const int z = i >> 6, j = i & 63;
    const int by = j >> 3, bx = j & 7;
    const unsigned short* A = Qb + (size_t)z * 2097152 + (size_t)by * 256 * 1024;
    const unsigned short* B = Kb + (size_t)z * 2097152 + (size_t)bx * 256 * 1024;
    floatx16 acc[4][2];
#pragma unroll
    for (int q = 0; q < 4; ++q)
#pragma unroll
        for (int h = 0; h < 2; ++h)
#pragma unroll
            for (int r = 0; r < 16; ++r) acc[q][h][r] = 0.f;

    gemm256_core(A, 1024, B, 1024, 1024, As, Bs, acc);

    const int tid = threadIdx.x;
    const int wave = tid >> 6, lane = tid & 63;
    const int wm = wave >> 2, wn = wave & 3;
    const int kg = lane >> 5, l31 = lane & 31;
    unsigned short* C = Sb + (size_t)z * 4194304;
    float* lz = l + z * 2048;
    const int rowbase = by * 256 + wm * 64;
    const int colbase = bx * 256 + wn * 32 + l31;
    // quadrant pairs sharing rows: qm=0 -> q0 (qn0) + q1 (qn1); qm=1 -> q3 + q2
#pragma unroll
    for (int h = 0; h < 2; ++h) {
        const int qA = h ? 3 : 0;   // qn = 0
        const int qB = h ? 2 : 1;   // qn = 1
#pragma unroll
        for (int mt = 0; mt < 2; ++mt)
#pragma unroll
            for (int r = 0; r < 16; ++r) {
                const int row = rowbase + h * 128 + mt * 32 + EPI_ROW(r, kg);
                const float e0 = __expf(acc[qA][mt][r] * 0.03125f);
                const float e1 = __expf(acc[qB][mt][r] * 0.03125f);
                C[(size_t)row * 2048 + colbase] = f2bf(e0);
                C[(size_t)row * 2048 + colbase + 128] = f2bf(e1);
                float s = e0 + e1;
                s += __shfl_xor(s, 1);  s += __shfl_xor(s, 2);
                s += __shfl_xor(s, 4);  s += __shfl_xor(s, 8);
                s += __shfl_xor(s, 16);
                if (l31 == mt * 16 + r) atomicAdd(&lz[row], s);
            }
    }
}

// ============ out = (P_unnorm @ Vt^T) / l[row] (fp32 out) ============
__global__ __launch_bounds__(256, 4) void pv_kernel(
    const unsigned short* __restrict__ Sb, const unsigned short* __restrict__ Vt,
    const float* __restrict__ l, float* __restrict__ out) {
    __shared__ unsigned short As[128 * 64];
    __shared__ unsigned short Bs[128 * 64];
    const int i = blockIdx.x;                    // 0..511
    const int z = (i >> 1) & 3;
    const int slot = i >> 3;
    const int by = (i & 1) + 2 * (slot & 7);
    const int bx = slot >> 3;
    const unsigned short* A = Sb + (size_t)z * 4194304 + (size_t)by * 128 * 2048;
    const unsigned short* B = Vt + (size_t)z * 2097152 + (size_t)bx * 128 * 2048;
    floatx16 acc[2][2];
#pragma unroll
    for (int a = 0; a < 2; ++a)
#pragma unroll
        for (int bj = 0; bj < 2; ++bj)
#pragma unroll
            for (int r = 0; r < 16; ++r) acc[a][bj][r] = 0.f;

    gemm_core(A, 2048, B, 2048, 2048, As, Bs, acc);

    const int wave = threadIdx.x >> 6, lane = threadIdx.x & 63;
    const int kg = lane >> 5;
    float* C = out + (size_t)z * 2097152;
    const float* lz = l + z * 2048;
    const int cm = by * 128 + (wave >> 1) * 64;
    const int cn = bx * 128 + (wave & 1) * 64 + (lane & 31);
#pragma unroll
    for (int mt = 0; mt < 2; ++mt)
#pragma unroll
        for (int r = 0; r < 16; ++r) {
            const int row = cm + mt * 32 + EPI_ROW(r, kg);
            const float inv = 1.0f / lz[row];
            C[(size_t)row * 1024 + cn] = acc[mt][0][r] * inv;
            C[(size_t)row * 1024 + cn + 32] = acc[mt][1][r] * inv;
        }
}

extern "C" void kernel_launch(void* const* d_in, const int* in_sizes, int n_in,
                              void* d_out, int out_size, void* d_ws, size_t ws_size,
                              hipStream_t stream) {
    const float* x   = (const float*)d_in[0];
    const float* ctx = (const float*)d_in[1];
    const float* Wq  = (const float*)d_in[2];
    const float* bq  = (const float*)d_in[3];
    const float* Wk  = (const float*)d_in[4];
    const float* bk  = (const float*)d_in[5];
    const float* Wv  = (const float*)d_in[6];
    const float* bv  = (const float*)d_in[7];
    float* out = (float*)d_out;

    const size_t MB = 1024 * 1024;
    char* ws = (char*)d_ws;
    unsigned short* xb   = (unsigned short*)(ws + 0 * MB);
    unsigned short* cb   = (unsigned short*)(ws + 16 * MB);
    unsigned short* Qb   = (unsigned short*)(ws + 32 * MB);
    unsigned short* Kb   = (unsigned short*)(ws + 48 * MB);
    unsigned short* Vt   = (unsigned short*)(ws + 64 * MB);
    unsigned short* Wt0  = (unsigned short*)(ws + 80 * MB);
    unsigned short* WtKV = (unsigned short*)(ws + 82 * MB);
    unsigned short* Sb   = (unsigned short*)(ws + 86 * MB);
    float*          lrow = (float*)(ws + 118 * MB);   // 8192 fp32 row sums

    prep_kernel<<<16384 + 3072 + 8, 256, 0, stream>>>(x, ctx, Wq, Wk, Wv, xb, cb, Wt0, WtKV, lrow);
    qkv_kv_kernel<<<256, 512, 0, stream>>>(cb, WtKV, bk, bv, Kb, Vt);
    qkv_q_kernel<<<512, 256, 0, stream>>>(xb, Wt0, bq, Qb);
    qkt_kernel<<<256, 512, 0, stream>>>(Qb, Kb, Sb, lrow);
    pv_kernel<<<512, 256, 0, stream>>>(Sb, Vt, lrow, out);
}

// Round 6
// 271.351 us; speedup vs baseline: 1.0731x; 1.0537x over previous
//
#include <hip/hip_runtime.h>
#include <cstdint>
#include <cstddef>

typedef __attribute__((ext_vector_type(8))) short short8;
typedef __attribute__((ext_vector_type(16))) float floatx16;

__device__ __forceinline__ unsigned short f2bf(float f) {
    union { float f; unsigned int u; } v; v.f = f;
    unsigned int r = v.u + 0x7fffu + ((v.u >> 16) & 1u);
    return (unsigned short)(r >> 16);
}

__device__ __forceinline__ void glds16(const void* g, void* l) {
    __builtin_amdgcn_global_load_lds(
        (const __attribute__((address_space(1))) void*)g,
        (__attribute__((address_space(3))) void*)l, 16, 0, 0);
}

// C/D layout (m74/m101, verified): col = lane&31, row = (r&3)+8*(r>>2)+4*kg
#define EPI_ROW(r, kg) (((r) & 3) + 8 * ((r) >> 2) + 4 * (kg))

// ============ 128x128 core, 2-barrier loop (measured 810 TF @ 4 blk/CU) ======
// Swizzle (verified: SQ_LDS_BANK_CONFLICT == 0): key(row)=(row^(row>>3))&7
__device__ __forceinline__ void gemm_core(
    const unsigned short* __restrict__ Ab, int ldA,
    const unsigned short* __restrict__ Bb, int ldB,
    int K,
    unsigned short* __restrict__ As, unsigned short* __restrict__ Bs,
    floatx16 (&acc)[2][2])
{
    const int tid = threadIdx.x;
    const int wave = tid >> 6, lane = tid & 63;

    const unsigned short* gA[4];
    const unsigned short* gB[4];
#pragma unroll
    for (int i = 0; i < 4; ++i) {
        const int c = i * 256 + tid;
        const int row = c >> 3;
        const int l = (c & 7) ^ ((row ^ (row >> 3)) & 7);
        gA[i] = Ab + (size_t)row * ldA + l * 8;
        gB[i] = Bb + (size_t)row * ldB + l * 8;
    }
    const int arow = (wave >> 1) * 64 + (lane & 31);
    const int brow = (wave & 1) * 64 + (lane & 31);
    const int kg = lane >> 5;
    const int sw = (lane & 7) ^ ((lane >> 3) & 3);
    const unsigned short* pa = As + arow * 64;
    const unsigned short* pb = Bs + brow * 64;

    for (int k0 = 0; k0 < K; k0 += 64) {
#pragma unroll
        for (int i = 0; i < 4; ++i)
            glds16(gA[i] + k0, As + (size_t)(i * 256 + wave * 64) * 8);
#pragma unroll
        for (int i = 0; i < 4; ++i)
            glds16(gB[i] + k0, Bs + (size_t)(i * 256 + wave * 64) * 8);
        __syncthreads();
#pragma unroll
        for (int s = 0; s < 4; ++s) {
            const int o0 = ((2 * s + kg) ^ sw) * 8;
            const int o1 = o0 ^ 32;
            short8 a0 = *(const short8*)(pa + o0);
            short8 a1 = *(const short8*)(pa + 32 * 64 + o1);
            short8 b0 = *(const short8*)(pb + o0);
            short8 b1 = *(const short8*)(pb + 32 * 64 + o1);
            acc[0][0] = __builtin_amdgcn_mfma_f32_32x32x16_bf16(a0, b0, acc[0][0], 0, 0, 0);
            acc[0][1] = __builtin_amdgcn_mfma_f32_32x32x16_bf16(a0, b1, acc[0][1], 0, 0, 0);
            acc[1][0] = __builtin_amdgcn_mfma_f32_32x32x16_bf16(a1, b0, acc[1][0], 0, 0, 0);
            acc[1][1] = __builtin_amdgcn_mfma_f32_32x32x16_bf16(a1, b1, acc[1][1], 0, 0, 0);
        }
        __syncthreads();
    }
}

// ====== prep: fp32->bf16 converts + weight transpose-converts + lrow zero ====
// (R3-validated variant: lrow zeroing folded in, removes the memset dispatch)
__global__ __launch_bounds__(256) void prep_kernel(
    const float* __restrict__ x, const float* __restrict__ ctx,
    const float* __restrict__ Wq, const float* __restrict__ Wk, const float* __restrict__ Wv,
    unsigned short* __restrict__ xb, unsigned short* __restrict__ cb,
    unsigned short* __restrict__ Wt0, unsigned short* __restrict__ WtKV,
    float* __restrict__ lrow) {
    const int b = blockIdx.x;
    if (b < 16384) {
        int i = b * 256 + threadIdx.x;
        const float* in; unsigned short* out; int j;
        if (i < 2097152) { in = x; out = xb; j = i; }
        else { in = ctx; out = cb; j = i - 2097152; }
        float4 v = reinterpret_cast<const float4*>(in)[j];
        ushort4 o;
        o.x = f2bf(v.x); o.y = f2bf(v.y); o.z = f2bf(v.z); o.w = f2bf(v.w);
        reinterpret_cast<ushort4*>(out)[j] = o;
    } else if (b < 19456) {
        __shared__ float tile[32][33];
        const int z = b - 16384;
        const int w = z >> 10, t = z & 1023;
        const float* in = (w == 0) ? Wq : (w == 1) ? Wk : Wv;
        unsigned short* out = (w == 0) ? Wt0 : (w == 1) ? WtKV : (WtKV + 1024 * 1024);
        const int c0 = (t & 31) * 32, r0 = (t >> 5) * 32;
        const int tx = threadIdx.x & 31, ty = threadIdx.x >> 5;
#pragma unroll
        for (int j = 0; j < 4; ++j)
            tile[ty + j * 8][tx] = in[(size_t)(r0 + ty + j * 8) * 1024 + c0 + tx];
        __syncthreads();
#pragma unroll
        for (int j = 0; j < 4; ++j)
            out[(size_t)(c0 + ty + j * 8) * 1024 + r0 + tx] = f2bf(tile[tx][ty + j * 8]);
    } else {
        // zero lrow: 8192 floats = 2048 float4 over 8 blocks x 256 threads
        const int i = (b - 19456) * 256 + threadIdx.x;
        reinterpret_cast<float4*>(lrow)[i] = float4{0.f, 0.f, 0.f, 0.f};
    }
}

// ============ mega QKV: 1536 blocks of 128x128; Q (512) + KV (1024) ==========
// (R0-verified: 63.6 us, MfmaUtil 33%, FETCH ~52 MB, i%8==by%8 XCD co-location)
__global__ __launch_bounds__(256, 4) void qkv_kernel(
    const unsigned short* __restrict__ xb, const unsigned short* __restrict__ cb,
    const unsigned short* __restrict__ WtQ, const unsigned short* __restrict__ WtKV,
    const float* __restrict__ bq, const float* __restrict__ bk, const float* __restrict__ bv,
    unsigned short* __restrict__ Qb, unsigned short* __restrict__ Kb,
    unsigned short* __restrict__ Vt) {
    __shared__ unsigned short As[128 * 64];
    __shared__ unsigned short Bs[128 * 64];
    const int i = blockIdx.x;
    const bool isQ = i < 512;
    int by, bxcol;
    const unsigned short *A, *B;
    if (isQ) {
        const int slot = i >> 3;
        by = (i & 7) + 8 * (slot & 7);
        const int bx = slot >> 3; bxcol = bx * 128;
        A = xb + (size_t)by * 128 * 1024;
        B = WtQ + (size_t)bx * 128 * 1024;
    } else {
        const int j = i - 512;
        const int slot = j >> 3;
        by = (j & 7) + 8 * (slot & 7);
        const int bx = slot >> 3; bxcol = bx * 128;
        A = cb + (size_t)by * 128 * 1024;
        B = WtKV + (size_t)bx * 128 * 1024;
    }
    floatx16 acc[2][2];
#pragma unroll
    for (int a = 0; a < 2; ++a)
#pragma unroll
        for (int bj = 0; bj < 2; ++bj)
#pragma unroll
            for (int r = 0; r < 16; ++r) acc[a][bj][r] = 0.f;

    gemm_core(A, 1024, B, 1024, 1024, As, Bs, acc);

    const int wave = threadIdx.x >> 6, lane = threadIdx.x & 63;
    const int kg = lane >> 5;
    const int cm = by * 128 + (wave >> 1) * 64;
    const int cn = bxcol + (wave & 1) * 64 + (lane & 31);
    if (isQ || bxcol < 1024) {
        unsigned short* O = isQ ? Qb : Kb;
        const float* bias = isQ ? bq : bk;
#pragma unroll
        for (int nt = 0; nt < 2; ++nt) {
            const int col = cn + nt * 32;
            const float bvv = bias[col];
#pragma unroll
            for (int mt = 0; mt < 2; ++mt)
#pragma unroll
                for (int r = 0; r < 16; ++r) {
                    const int row = cm + mt * 32 + EPI_ROW(r, kg);
                    O[(size_t)row * 1024 + col] = f2bf(acc[mt][nt][r] + bvv);
                }
        }
    } else {
        // V half -> transposed write: Vt[b][colv][q]; 4 consecutive q per reg-quad
#pragma unroll
        for (int nt = 0; nt < 2; ++nt) {
            const int colv = cn + nt * 32 - 1024;
            const float bvv = bv[colv];
#pragma unroll
            for (int mt = 0; mt < 2; ++mt) {
                const int rowg = cm + mt * 32 + 4 * kg;
                const int b = rowg >> 11, qb = rowg & 2047;
#pragma unroll
                for (int g = 0; g < 4; ++g) {
                    const int q = qb + 8 * g;
                    ushort4 u;
                    u.x = f2bf(acc[mt][nt][g * 4 + 0] + bvv);
                    u.y = f2bf(acc[mt][nt][g * 4 + 1] + bvv);
                    u.z = f2bf(acc[mt][nt][g * 4 + 2] + bvv);
                    u.w = f2bf(acc[mt][nt][g * 4 + 3] + bvv);
                    *reinterpret_cast<ushort4*>(Vt + (size_t)b * 2097152 + (size_t)colv * 2048 + q) = u;
                }
            }
        }
    }
}

// ============ P_unnorm = exp(Q K^T * scale); row sums -> l via atomics ========
// (R0-verified body; logits bounded so no max-subtract needed)
__global__ __launch_bounds__(256, 4) void qkt_kernel(
    const unsigned short* __restrict__ Qb, const unsigned short* __restrict__ Kb,
    unsigned short* __restrict__ Sb, float* __restrict__ l) {
    __shared__ unsigned short As[128 * 64];
    __shared__ unsigned short Bs[128 * 64];
    const int i = blockIdx.x;                    // 0..1023
    const int z = (i >> 1) & 3;
    const int slot = i >> 3;
    const int by = (i & 1) + 2 * (slot & 7);
    const int bx = slot >> 3;
    const unsigned short* A = Qb + (size_t)z * 2097152 + (size_t)by * 128 * 1024;
    const unsigned short* B = Kb + (size_t)z * 2097152 + (size_t)bx * 128 * 1024;
    floatx16 acc[2][2];
#pragma unroll
    for (int a = 0; a < 2; ++a)
#pragma unroll
        for (int bj = 0; bj < 2; ++bj)
#pragma unroll
            for (int r = 0; r < 16; ++r) acc[a][bj][r] = 0.f;

    gemm_core(A, 1024, B, 1024, 1024, As, Bs, acc);

    const int wave = threadIdx.x >> 6, lane = threadIdx.x & 63;
    const int kg = lane >> 5;
    unsigned short* C = Sb + (size_t)z * 4194304;
    float* lz = l + z * 2048;
    const int cm = by * 128 + (wave >> 1) * 64;
    const int cn = bx * 128 + (wave & 1) * 64 + (lane & 31);
#pragma unroll
    for (int mt = 0; mt < 2; ++mt)
#pragma unroll
        for (int r = 0; r < 16; ++r) {
            const int row = cm + mt * 32 + EPI_ROW(r, kg);
            const float e0 = __expf(acc[mt][0][r] * 0.03125f);
            const float e1 = __expf(acc[mt][1][r] * 0.03125f);
            C[(size_t)row * 2048 + cn] = f2bf(e0);
            C[(size_t)row * 2048 + cn + 32] = f2bf(e1);
            float s = e0 + e1;
            s += __shfl_xor(s, 1);  s += __shfl_xor(s, 2);
            s += __shfl_xor(s, 4);  s += __shfl_xor(s, 8);
            s += __shfl_xor(s, 16);
            if ((lane & 31) == (mt * 16 + r)) atomicAdd(&lz[row], s);
        }
}

// ============ out = (P_unnorm @ Vt^T) / l[row] (fp32 out) ============
// (R0-verified body)
__global__ __launch_bounds__(256, 4) void pv_kernel(
    const unsigned short* __restrict__ Sb, const unsigned short* __restrict__ Vt,
    const float* __restrict__ l, float* __restrict__ out) {
    __shared__ unsigned short As[128 * 64];
    __shared__ unsigned short Bs[128 * 64];
    const int i = blockIdx.x;                    // 0..511
    const int z = (i >> 1) & 3;
    const int slot = i >> 3;
    const int by = (i & 1) + 2 * (slot & 7);
    const int bx = slot >> 3;
    const unsigned short* A = Sb + (size_t)z * 4194304 + (size_t)by * 128 * 2048;
    const unsigned short* B = Vt + (size_t)z * 2097152 + (size_t)bx * 128 * 2048;
    floatx16 acc[2][2];
#pragma unroll
    for (int a = 0; a < 2; ++a)
#pragma unroll
        for (int bj = 0; bj < 2; ++bj)
#pragma unroll
            for (int r = 0; r < 16; ++r) acc[a][bj][r] = 0.f;

    gemm_core(A, 2048, B, 2048, 2048, As, Bs, acc);

    const int wave = threadIdx.x >> 6, lane = threadIdx.x & 63;
    const int kg = lane >> 5;
    float* C = out + (size_t)z * 2097152;
    const float* lz = l + z * 2048;
    const int cm = by * 128 + (wave >> 1) * 64;
    const int cn = bx * 128 + (wave & 1) * 64 + (lane & 31);
#pragma unroll
    for (int mt = 0; mt < 2; ++mt)
#pragma unroll
        for (int r = 0; r < 16; ++r) {
            const int row = cm + mt * 32 + EPI_ROW(r, kg);
            const float inv = 1.0f / lz[row];
            C[(size_t)row * 1024 + cn] = acc[mt][0][r] * inv;
            C[(size_t)row * 1024 + cn + 32] = acc[mt][1][r] * inv;
        }
}

extern "C" void kernel_launch(void* const* d_in, const int* in_sizes, int n_in,
                              void* d_out, int out_size, void* d_ws, size_t ws_size,
                              hipStream_t stream) {
    const float* x   = (const float*)d_in[0];
    const float* ctx = (const float*)d_in[1];
    const float* Wq  = (const float*)d_in[2];
    const float* bq  = (const float*)d_in[3];
    const float* Wk  = (const float*)d_in[4];
    const float* bk  = (const float*)d_in[5];
    const float* Wv  = (const float*)d_in[6];
    const float* bv  = (const float*)d_in[7];
    float* out = (float*)d_out;

    const size_t MB = 1024 * 1024;
    char* ws = (char*)d_ws;
    unsigned short* xb   = (unsigned short*)(ws + 0 * MB);
    unsigned short* cb   = (unsigned short*)(ws + 16 * MB);
    unsigned short* Qb   = (unsigned short*)(ws + 32 * MB);
    unsigned short* Kb   = (unsigned short*)(ws + 48 * MB);
    unsigned short* Vt   = (unsigned short*)(ws + 64 * MB);
    unsigned short* Wt0  = (unsigned short*)(ws + 80 * MB);
    unsigned short* WtKV = (unsigned short*)(ws + 82 * MB);
    unsigned short* Sb   = (unsigned short*)(ws + 86 * MB);
    float*          lrow = (float*)(ws + 118 * MB);   // 8192 fp32 row sums

    prep_kernel<<<16384 + 3072 + 8, 256, 0, stream>>>(
        x, ctx, Wq, Wk, Wv, xb, cb, Wt0, WtKV, lrow);
    qkv_kernel<<<1536, 256, 0, stream>>>(xb, cb, Wt0, WtKV, bq, bk, bv, Qb, Kb, Vt);
    qkt_kernel<<<1024, 256, 0, stream>>>(Qb, Kb, Sb, lrow);
    pv_kernel<<<512, 256, 0, stream>>>(Sb, Vt, lrow, out);
}